// Round 1
// baseline (3131.957 us; speedup 1.0000x reference)
//
#include <hip/hip_runtime.h>
#include <cstdint>
#include <cstddef>

// Problem constants
#define M_TOK   1232      // B*S
#define D_MODEL 2048
#define F_FFN   8192
#define SEQ     77
#define BATCH   16
#define NHEAD   16
#define LRANK   16
#define NLAYER  2

typedef short bf16x8 __attribute__((ext_vector_type(8)));
typedef float f32x4  __attribute__((ext_vector_type(4)));

__device__ __constant__ float NF4C[16] = {
  -1.0f, -0.6961928009986877f, -0.5250730514526367f, -0.39491748809814453f,
  -0.28444138169288635f, -0.18477343022823334f, -0.09105003625154495f, 0.0f,
  0.07958029955625534f, 0.16093020141124725f, 0.24611230194568634f,
  0.33791524171829224f, 0.44070982933044434f, 0.5626170039176941f,
  0.723855197429657f, 1.0f };

__device__ inline short f2b(float f) {
  unsigned u = __builtin_bit_cast(unsigned, f);
  u += 0x7FFFu + ((u >> 16) & 1u);   // round-to-nearest-even
  return (short)(u >> 16);
}

// ---------------------------------------------------------------------------
// Fused NF4-dequant GEMM:  O[M][N] (+)= X[M][K] @ W^T, W[n][k]=NF4[C[n][k]]*AM[n][k/64]
// 64x64 tile, BK=64, 4 waves, each wave a 32x32 quadrant via 2x2 16x16x32 MFMA.
// ---------------------------------------------------------------------------
__global__ __launch_bounds__(256) void gemm_dq(
    const float* __restrict__ X, const int* __restrict__ C,
    const float* __restrict__ AM, float* __restrict__ O,
    int M, int N, int K, int acc_mode)
{
  __shared__ short xs[64][72];   // 72: 16B-aligned rows (144 B stride), conflict pad
  __shared__ short ws[64][72];
  __shared__ float nf4s[16];
  int tid = threadIdx.x;
  if (tid < 16) nf4s[tid] = NF4C[tid];

  int row0 = blockIdx.x * 64, col0 = blockIdx.y * 64;
  int srow = tid >> 2, scol = (tid & 3) << 4;   // staging: 16 elems/thread
  int wave = tid >> 6, lane = tid & 63;
  int wm = (wave >> 1) * 32, wn = (wave & 1) * 32;
  int fr = lane & 15, fg = lane >> 4;

  f32x4 acc[2][2];
  #pragma unroll
  for (int i = 0; i < 2; ++i)
    #pragma unroll
    for (int j = 0; j < 2; ++j)
      acc[i][j] = (f32x4){0.f, 0.f, 0.f, 0.f};

  const int KB = K >> 6;  // also absmax stride per row
  for (int kt = 0; kt < KB; ++kt) {
    __syncthreads();
    { // stage X (f32 -> bf16)
      int gm = row0 + srow;
      if (gm < M) {
        const float4* p = (const float4*)(X + (size_t)gm * K + (kt << 6) + scol);
        #pragma unroll
        for (int v2 = 0; v2 < 4; ++v2) {
          float4 f = p[v2];
          xs[srow][scol + v2*4 + 0] = f2b(f.x);
          xs[srow][scol + v2*4 + 1] = f2b(f.y);
          xs[srow][scol + v2*4 + 2] = f2b(f.z);
          xs[srow][scol + v2*4 + 3] = f2b(f.w);
        }
      } else {
        #pragma unroll
        for (int v2 = 0; v2 < 16; ++v2) xs[srow][scol + v2] = 0;
      }
    }
    { // stage W with NF4 dequant (int32 code -> bf16)
      int gn = col0 + srow;
      float am = AM[(size_t)gn * KB + kt];
      const int4* p = (const int4*)(C + (size_t)gn * K + (kt << 6) + scol);
      #pragma unroll
      for (int v2 = 0; v2 < 4; ++v2) {
        int4 c = p[v2];
        ws[srow][scol + v2*4 + 0] = f2b(nf4s[c.x] * am);
        ws[srow][scol + v2*4 + 1] = f2b(nf4s[c.y] * am);
        ws[srow][scol + v2*4 + 2] = f2b(nf4s[c.z] * am);
        ws[srow][scol + v2*4 + 3] = f2b(nf4s[c.w] * am);
      }
    }
    __syncthreads();
    #pragma unroll
    for (int kk = 0; kk < 2; ++kk) {
      int kb = kk*32 + fg*8;
      bf16x8 a0 = *(const bf16x8*)&xs[wm + fr][kb];
      bf16x8 a1 = *(const bf16x8*)&xs[wm + 16 + fr][kb];
      bf16x8 b0 = *(const bf16x8*)&ws[wn + fr][kb];
      bf16x8 b1 = *(const bf16x8*)&ws[wn + 16 + fr][kb];
      acc[0][0] = __builtin_amdgcn_mfma_f32_16x16x32_bf16(a0, b0, acc[0][0], 0, 0, 0);
      acc[0][1] = __builtin_amdgcn_mfma_f32_16x16x32_bf16(a0, b1, acc[0][1], 0, 0, 0);
      acc[1][0] = __builtin_amdgcn_mfma_f32_16x16x32_bf16(a1, b0, acc[1][0], 0, 0, 0);
      acc[1][1] = __builtin_amdgcn_mfma_f32_16x16x32_bf16(a1, b1, acc[1][1], 0, 0, 0);
    }
  }
  // C/D layout (verified m89/m91): col = lane&15, row = (lane>>4)*4 + reg
  #pragma unroll
  for (int mi = 0; mi < 2; ++mi)
    #pragma unroll
    for (int ni = 0; ni < 2; ++ni)
      #pragma unroll
      for (int r = 0; r < 4; ++r) {
        int gm = row0 + wm + mi*16 + fg*4 + r;
        int gn = col0 + wn + ni*16 + fr;
        if (gm < M) {
          size_t idx = (size_t)gm * N + gn;
          float vv = acc[mi][ni][r];
          O[idx] = acc_mode ? (O[idx] + vv) : vv;
        }
      }
}

// ---------------------------------------------------------------------------
// LoRA stage 1: T[m][r] = sum_k X[m][k] * A[r][k]   (R=16)
// one block per row m; 16 groups of 16 lanes, each group one r
// ---------------------------------------------------------------------------
__global__ __launch_bounds__(256) void lora1(
    const float* __restrict__ X, const float* __restrict__ A,
    float* __restrict__ T, int K)
{
  int m = blockIdx.x;
  int g = threadIdx.x >> 4, l16 = threadIdx.x & 15;
  const float* xr = X + (size_t)m * K;
  const float* ar = A + (size_t)g * K;
  float s = 0.f;
  for (int kk = l16; kk < K; kk += 16) s += xr[kk] * ar[kk];
  #pragma unroll
  for (int off = 8; off; off >>= 1) s += __shfl_down(s, off, 16);
  if (l16 == 0) T[m * LRANK + g] = s;
}

// LoRA stage 2: O[m][n] += 2.0 * sum_r T[m][r] * Bm[n][r]
__global__ __launch_bounds__(256) void lora2(
    float* __restrict__ O, const float* __restrict__ T,
    const float* __restrict__ Bm, int N)
{
  int m = blockIdx.y;
  int n = blockIdx.x * 256 + threadIdx.x;
  __shared__ float ts[LRANK];
  if (threadIdx.x < LRANK) ts[threadIdx.x] = T[m * LRANK + threadIdx.x];
  __syncthreads();
  const float4* br = (const float4*)(Bm + (size_t)n * LRANK);
  float s = 0.f;
  #pragma unroll
  for (int v2 = 0; v2 < 4; ++v2) {
    float4 b = br[v2];
    s += b.x * ts[v2*4+0] + b.y * ts[v2*4+1] + b.z * ts[v2*4+2] + b.w * ts[v2*4+3];
  }
  O[(size_t)m * N + n] += 2.0f * s;
}

// ---------------------------------------------------------------------------
__global__ __launch_bounds__(256) void rmsnorm_k(
    const float* __restrict__ H, const float* __restrict__ W,
    float* __restrict__ X, int D)
{
  int m = blockIdx.x;
  const float* hr = H + (size_t)m * D;
  float s = 0.f;
  for (int i = threadIdx.x; i < D; i += 256) { float v = hr[i]; s += v * v; }
  __shared__ float red[4];
  #pragma unroll
  for (int off = 32; off; off >>= 1) s += __shfl_down(s, off, 64);
  if ((threadIdx.x & 63) == 0) red[threadIdx.x >> 6] = s;
  __syncthreads();
  float tot = red[0] + red[1] + red[2] + red[3];
  float inv = rsqrtf(tot / (float)D + 1e-6f);
  for (int i = threadIdx.x; i < D; i += 256)
    X[(size_t)m * D + i] = hr[i] * inv * W[i];
}

__global__ void rope_table(float* __restrict__ cosT, float* __restrict__ sinT)
{
  int idx = blockIdx.x * 64 + threadIdx.x;
  if (idx >= SEQ * 64) return;
  int s = idx >> 6, j = idx & 63;
  float inv = powf(10000.0f, -(float)(2 * j) / 128.0f);
  float f = (float)s * inv;
  cosT[idx] = cosf(f);
  sinT[idx] = sinf(f);
}

__global__ void rope_apply(float* __restrict__ Q, float* __restrict__ Kb,
                           const float* __restrict__ cosT, const float* __restrict__ sinT)
{
  size_t idx = (size_t)blockIdx.x * 256 + threadIdx.x;
  if (idx >= (size_t)M_TOK * NHEAD * 64) return;
  int j = idx & 63;
  int h = (idx >> 6) & (NHEAD - 1);
  int m = (int)(idx >> 10);
  int s = m % SEQ;
  float c = cosT[s * 64 + j], sn = sinT[s * 64 + j];
  size_t base = (size_t)m * D_MODEL + h * 128;
  float q1 = Q[base + j], q2 = Q[base + 64 + j];
  Q[base + j]      = q1 * c - q2 * sn;
  Q[base + 64 + j] = q2 * c + q1 * sn;
  float k1 = Kb[base + j], k2 = Kb[base + 64 + j];
  Kb[base + j]      = k1 * c - k2 * sn;
  Kb[base + 64 + j] = k2 * c + k1 * sn;
}

// attention: one block per (b,h), scores in LDS, 3 phases
__global__ __launch_bounds__(256) void attn_k(
    const float* __restrict__ Q, const float* __restrict__ Kb,
    const float* __restrict__ V, const int* __restrict__ amask,
    float* __restrict__ O)
{
  int bh = blockIdx.x;
  int b = bh / NHEAD, h = bh % NHEAD;
  __shared__ float sc[SEQ * SEQ];
  const float scale = 0.08838834764831845f;  // 1/sqrt(128)
  for (int idx = threadIdx.x; idx < SEQ * SEQ; idx += 256) {
    int i = idx / SEQ, j = idx % SEQ;
    float val = -1e9f;
    if (j <= i && amask[b * SEQ + j] != 0) {
      const float4* qr = (const float4*)(Q + ((size_t)(b*SEQ+i) * D_MODEL) + h*128);
      const float4* kr = (const float4*)(Kb + ((size_t)(b*SEQ+j) * D_MODEL) + h*128);
      float s = 0.f;
      #pragma unroll 8
      for (int d = 0; d < 32; ++d) {
        float4 a = qr[d], c = kr[d];
        s += a.x*c.x + a.y*c.y + a.z*c.z + a.w*c.w;
      }
      val = s * scale;
    }
    sc[idx] = val;
  }
  __syncthreads();
  for (int i = threadIdx.x; i < SEQ; i += 256) {
    float mx = -1e30f;
    for (int j = 0; j < SEQ; ++j) mx = fmaxf(mx, sc[i*SEQ+j]);
    float sum = 0.f;
    for (int j = 0; j < SEQ; ++j) { float e = expf(sc[i*SEQ+j] - mx); sc[i*SEQ+j] = e; sum += e; }
    float inv = 1.0f / sum;
    for (int j = 0; j < SEQ; ++j) sc[i*SEQ+j] *= inv;
  }
  __syncthreads();
  for (int idx = threadIdx.x; idx < SEQ * 128; idx += 256) {
    int i = idx >> 7, d = idx & 127;
    float s = 0.f;
    for (int j = 0; j < SEQ; ++j)
      s += sc[i*SEQ+j] * V[((size_t)(b*SEQ+j) * D_MODEL) + h*128 + d];
    O[((size_t)(b*SEQ+i) * D_MODEL) + h*128 + d] = s;
  }
}

__global__ void embed_gather(const float* __restrict__ E, const int* __restrict__ ids,
                             float* __restrict__ H)
{
  size_t idx = (size_t)blockIdx.x * 256 + threadIdx.x;
  int m = (int)(idx / D_MODEL);
  int n = (int)(idx % D_MODEL);
  H[idx] = E[(size_t)ids[m] * D_MODEL + n];
}

__global__ void silu_mul(float* __restrict__ G, const float* __restrict__ U)
{
  size_t idx = (size_t)blockIdx.x * 256 + threadIdx.x;
  float g = G[idx];
  float sig = 1.0f / (1.0f + expf(-g));
  G[idx] = g * sig * U[idx];
}

__global__ __launch_bounds__(256) void final_k(
    const float* __restrict__ H, const int* __restrict__ amask,
    const float* __restrict__ W, float* __restrict__ out)
{
  int b = blockIdx.x;
  __shared__ int len;
  if (threadIdx.x == 0) {
    int s = 0;
    for (int j = 0; j < SEQ; ++j) s += amask[b * SEQ + j];
    len = s - 1;
  }
  __syncthreads();
  const float* hr = H + ((size_t)(b * SEQ + len) * D_MODEL);
  float s = 0.f;
  for (int i = threadIdx.x; i < D_MODEL; i += 256) { float v = hr[i]; s += v * v; }
  __shared__ float red[4];
  #pragma unroll
  for (int off = 32; off; off >>= 1) s += __shfl_down(s, off, 64);
  if ((threadIdx.x & 63) == 0) red[threadIdx.x >> 6] = s;
  __syncthreads();
  float tot = red[0] + red[1] + red[2] + red[3];
  float inv = rsqrtf(tot / (float)D_MODEL + 1e-6f);
  for (int i = threadIdx.x; i < D_MODEL; i += 256)
    out[(size_t)b * D_MODEL + i] = hr[i] * inv * W[i];
}

// ---------------------------------------------------------------------------
extern "C" void kernel_launch(void* const* d_in, const int* in_sizes, int n_in,
                              void* d_out, int out_size, void* d_ws, size_t ws_size,
                              hipStream_t stream) {
  const int*   ids     = (const int*)d_in[0];
  const int*   amask   = (const int*)d_in[1];
  const float* embed   = (const float*)d_in[2];
  const float* ln_attn = (const float*)d_in[3];
  const float* ln_mlp  = (const float*)d_in[4];
  const float* ln_fin  = (const float*)d_in[5];
  const int*   qkvC    = (const int*)d_in[6];
  const float* qkvS    = (const float*)d_in[7];
  const float* qkvA    = (const float*)d_in[8];
  const float* qkvB    = (const float*)d_in[9];
  const int*   oC      = (const int*)d_in[10];
  const float* oS      = (const float*)d_in[11];
  const float* oA      = (const float*)d_in[12];
  const float* oB      = (const float*)d_in[13];
  const int*   guC     = (const int*)d_in[14];
  const float* guS     = (const float*)d_in[15];
  const float* guA     = (const float*)d_in[16];
  const float* guB     = (const float*)d_in[17];
  const int*   dnC     = (const int*)d_in[18];
  const float* dnS     = (const float*)d_in[19];
  const float* dnA     = (const float*)d_in[20];
  const float* dnB     = (const float*)d_in[21];
  float* out = (float*)d_out;

  const int M = M_TOK;
  float* p = (float*)d_ws;
  float* h   = p; p += (size_t)M * D_MODEL;
  float* x   = p; p += (size_t)M * D_MODEL;
  float* q   = p; p += (size_t)M * D_MODEL;
  float* k   = p; p += (size_t)M * D_MODEL;
  float* v   = p; p += (size_t)M * D_MODEL;
  float* g   = p; p += (size_t)M * F_FFN;
  float* up  = p; p += (size_t)M * F_FFN;
  float* t   = p; p += (size_t)M * LRANK;
  float* cosT = p; p += SEQ * 64;
  float* sinT = p; p += SEQ * 64;

  rope_table<<<(SEQ*64 + 63)/64, 64, 0, stream>>>(cosT, sinT);
  embed_gather<<<(M * D_MODEL)/256, 256, 0, stream>>>(embed, ids, h);

  auto qlora = [&](const float* xin, const int* C, const float* AM,
                   const float* A, const float* Bm, float* outb,
                   int N, int K, int accum) {
    gemm_dq<<<dim3((M + 63)/64, N/64), 256, 0, stream>>>(xin, C, AM, outb, M, N, K, accum);
    lora1<<<M, 256, 0, stream>>>(xin, A, t, K);
    lora2<<<dim3(N/256, M), 256, 0, stream>>>(outb, t, Bm, N);
  };

  for (int l = 0; l < NLAYER; ++l) {
    rmsnorm_k<<<M, 256, 0, stream>>>(h, ln_attn + (size_t)l * D_MODEL, x, D_MODEL);
    float* qkv_out[3] = {q, k, v};
    for (int i = 0; i < 3; ++i) {
      size_t wi = (size_t)(l*3 + i);
      qlora(x, qkvC + wi * D_MODEL * D_MODEL, qkvS + wi * D_MODEL * (D_MODEL/64),
            qkvA + wi * LRANK * D_MODEL, qkvB + wi * D_MODEL * LRANK,
            qkv_out[i], D_MODEL, D_MODEL, 0);
    }
    rope_apply<<<((size_t)M*NHEAD*64 + 255)/256, 256, 0, stream>>>(q, k, cosT, sinT);
    attn_k<<<BATCH*NHEAD, 256, 0, stream>>>(q, k, v, amask, x);
    qlora(x, oC + (size_t)l * D_MODEL * D_MODEL, oS + (size_t)l * D_MODEL * (D_MODEL/64),
          oA + (size_t)l * LRANK * D_MODEL, oB + (size_t)l * D_MODEL * LRANK,
          h, D_MODEL, D_MODEL, 1);
    rmsnorm_k<<<M, 256, 0, stream>>>(h, ln_mlp + (size_t)l * D_MODEL, x, D_MODEL);
    float* gu_out[2] = {g, up};
    for (int i = 0; i < 2; ++i) {
      size_t wi = (size_t)(l*2 + i);
      qlora(x, guC + wi * (size_t)F_FFN * D_MODEL, guS + wi * (size_t)F_FFN * (D_MODEL/64),
            guA + wi * LRANK * D_MODEL, guB + wi * (size_t)F_FFN * LRANK,
            gu_out[i], F_FFN, D_MODEL, 0);
    }
    silu_mul<<<((size_t)M * F_FFN)/256, 256, 0, stream>>>(g, up);
    qlora(g, dnC + (size_t)l * D_MODEL * F_FFN, dnS + (size_t)l * D_MODEL * (F_FFN/64),
          dnA + (size_t)l * LRANK * F_FFN, dnB + (size_t)l * D_MODEL * LRANK,
          h, D_MODEL, F_FFN, 1);
  }
  final_k<<<BATCH, 256, 0, stream>>>(h, amask, ln_fin, out);
}